// Round 9
// baseline (1057.940 us; speedup 1.0000x reference)
//
#include <hip/hip_runtime.h>

#define NROWS 16384
#define DIM   512
#define BM    32
#define NT    256            // K tiles of 32 codes
#define KC    8192
#define QCAP  32768
#define MARGIN 0.05f
#define DEFER_THR 8.0f
#define LN2   0.69314718055994531f

typedef _Float16 half8  __attribute__((ext_vector_type(8)));
typedef float    f32x4  __attribute__((ext_vector_type(4)));

#define MFMA(a,b,c) __builtin_amdgcn_mfma_f32_16x16x32_f16(a,b,c,0,0,0)

__device__ __forceinline__ float flog2(float x){ return __builtin_amdgcn_logf(x); }
__device__ __forceinline__ float fexp2(float x){ return __builtin_amdgcn_exp2f(x); }
__device__ __forceinline__ f32x4 ntload4(const float* p){
  return __builtin_nontemporal_load((const f32x4*)p);
}

__device__ __forceinline__ void top2_merge(float& v1, int& i1, float& v2, int& i2,
                                           float bv1, int bi1, float bv2, int bi2) {
  bool takeB = (bv1 > v1) || (bv1 == v1 && bi1 < i1);
  float nv1 = takeB ? bv1 : v1; int ni1 = takeB ? bi1 : i1;
  float cv  = takeB ? v1  : bv1; int ci = takeB ? i1  : bi1;
  float ov2 = takeB ? bv2 : v2;  int oi = takeB ? bi2 : i2;
  bool cb = (cv > ov2) || (cv == ov2 && ci < oi);
  v2 = cb ? cv : ov2; i2 = cb ? ci : oi;
  v1 = nv1; i1 = ni1;
}

// ---------------- prep kernels ----------------
__global__ void prep_x(const float* __restrict__ x, _Float16* __restrict__ xh) {
  size_t i = (size_t)(blockIdx.x * blockDim.x + threadIdx.x) * 4;
  f32x4 v = *(const f32x4*)(x + i);
  _Float16 h4[4];
  h4[0] = (_Float16)(2.0f * v[0]); h4[1] = (_Float16)(2.0f * v[1]);
  h4[2] = (_Float16)(2.0f * v[2]); h4[3] = (_Float16)(2.0f * v[3]);
  *(uint2*)(xh + i) = *(uint2*)h4;
}

// codebook, frag-ordered [256 t][16 kc][32 code][4 u] f16 — each wave's A-frag
// read is one fully-contiguous 1KB region (lane = 16B). No swizzle (global, no banks).
__global__ void prep_cht2(const float* __restrict__ c, _Float16* __restrict__ cht) {
  const int gid = blockIdx.x * 256 + threadIdx.x;     // one 16B unit (8 d-values)
  const int code = gid >> 6, u = gid & 63;
  f32x4 v0 = *(const f32x4*)(c + (size_t)code * DIM + u * 8);
  f32x4 v1 = *(const f32x4*)(c + (size_t)code * DIM + u * 8 + 4);
  half8 h;
#pragma unroll
  for (int q = 0; q < 4; ++q) { h[q] = (_Float16)v0[q]; h[4+q] = (_Float16)v1[q]; }
  const int t = code >> 5, cc = code & 31, kc = u >> 2, ul = u & 3;
  *(half8*)((char*)cht + (size_t)t * 32768 + kc * 2048 + cc * 64 + ul * 16) = h;
}

// codebook^T, tiled [256 t][512 d][32 k] f16 (identical to R6)
__global__ void prep_ctt(const float* __restrict__ c, _Float16* __restrict__ ctt) {
  __shared__ _Float16 lt[64][72];
  const int kb = (blockIdx.x >> 3) * 64;
  const int db = (blockIdx.x & 7) * 64;
  {
    const int r = threadIdx.x >> 2, c4 = threadIdx.x & 3;
#pragma unroll
    for (int j = 0; j < 4; ++j) {
      f32x4 v = *(const f32x4*)(c + (size_t)(kb + r) * DIM + db + c4 * 16 + j * 4);
#pragma unroll
      for (int q = 0; q < 4; ++q) lt[r][c4 * 16 + j * 4 + q] = (_Float16)v[q];
    }
  }
  __syncthreads();
  {
    const int d = threadIdx.x >> 2, ks = threadIdx.x & 3;
    half8 o0, o1;
#pragma unroll
    for (int j = 0; j < 8; ++j) { o0[j] = lt[ks*16 + j][d]; o1[j] = lt[ks*16 + 8 + j][d]; }
    const int dg = db + d;
    const int t = (kb >> 5) + (ks >> 1);
    const int u0 = (ks & 1) * 2;
    char* base = (char*)ctt + (size_t)t * 32768 + (size_t)dg * 64;
    *(half8*)(base + ((u0       ^ (dg & 3)) << 4)) = o0;
    *(half8*)(base + (((u0 + 1) ^ (dg & 3)) << 4)) = o1;
  }
}

__global__ void prep_c2(const float* __restrict__ c, float* __restrict__ c2) {
  const int w = threadIdx.x >> 6, l = threadIdx.x & 63;
  const int code = blockIdx.x * 4 + w;
  double s = 0.0;
  for (int i = l; i < DIM; i += 64) { double v = c[(size_t)code * DIM + i]; s += v * v; }
#pragma unroll
  for (int o = 32; o; o >>= 1) s += __shfl_down(s, o, 64);
  if (l == 0) c2[code] = (float)s;
}

// ---------------- main fused kernel ----------------
// R6 structure, LDS QK path deleted: A-frags global-direct (af[16] regs, refilled
// after use with a full-tile latency window). Both barriers lgkm-only. LDS = p dbuf
// (4KB) + epilogue staging + tables = 39936 B. 512 blocks x 256 thr, 2 blocks/CU.
__global__ __launch_bounds__(256, 2) void vq_fused(
    const float* __restrict__ U, const _Float16* __restrict__ Xh,
    const _Float16* __restrict__ CHT2, const _Float16* __restrict__ CTT,
    const float* __restrict__ C2, const float* __restrict__ Tp,
    float* __restrict__ emb, float* __restrict__ ids,
    int* __restrict__ fixcnt, int* __restrict__ fixq) {
  __shared__ __align__(16) char smem[39936];
  const int tid = threadIdx.x;
  const int w = tid >> 6, l = tid & 63, l15 = l & 15, l4 = l >> 4;
  const int cs = w & 1, rs = w >> 1;
  const int row0 = blockIdx.x * BM;
  const float c1 = 1.4426950408889634f / Tp[0];   // log2e / T
  const char* CH2c = (const char*)CHT2;
  const char* CTTc = (const char*)CTT;

  // x rows resident in registers: row rs*16+l15, all 512 d
  half8 xr[16];
  {
    const _Float16* xb = Xh + (size_t)(row0 + rs*16 + l15) * DIM + l4 * 8;
#pragma unroll
    for (int kc = 0; kc < 16; ++kc) xr[kc] = *(const half8*)(xb + kc * 32);
  }

  const int sxp = (l15 ^ (l15 >> 2)) & 3;      // p LDS row-xor (4 units/row)
  const int prow = rs*16 + l15;                // p row this lane writes
  const int afo = (cs*16 + l15) * 64 + l4*16;  // lane offset within a kc frag block

  const float* ub  = U  + (size_t)(row0 + prow) * KC + cs*16 + l4*4;
  const float* c2p = C2 + cs*16 + l4*4;

  f32x4 upre  = ntload4(ub);
  f32x4 c2pre = *(const f32x4*)(c2p);

  // A-frags for tile 0 (global-direct, coalesced 1KB per load)
  half8 af[16];
#pragma unroll
  for (int kc = 0; kc < 16; ++kc)
    af[kc] = *(const half8*)(CH2c + kc * 2048 + afo);

  f32x4 O[8][2];   // [dt: d=w*128+dt*16][rt: row half]
#pragma unroll
  for (int a = 0; a < 8; ++a)
#pragma unroll
    for (int b = 0; b < 2; ++b) { O[a][b][0]=0.f; O[a][b][1]=0.f; O[a][b][2]=0.f; O[a][b][3]=0.f; }
  half8 ctf[8];
  float mO[2] = {-3e38f, -3e38f};              // per-row-half running maxes
  float l_run = 0.f;
  float v1 = -3e38f, v2 = -3e38f; int i1 = 0, i2 = 0;
  float* mtab = (float*)(smem + 37888);        // [4][16]

  __syncthreads();

#pragma unroll 1
  for (int t = 0; t < NT; ++t) {
    // 1. QK: S^T tile [16 codes x 16 rows], A from regs, split accumulator chains
    f32x4 ae = {0.f,0.f,0.f,0.f}, ao = {0.f,0.f,0.f,0.f};
#pragma unroll
    for (int j = 0; j < 8; ++j) {
      ae = MFMA(af[2*j],     xr[2*j],     ae);
      ao = MFMA(af[2*j + 1], xr[2*j + 1], ao);
    }
    f32x4 a0;
    a0[0] = ae[0] + ao[0]; a0[1] = ae[1] + ao[1];
    a0[2] = ae[2] + ao[2]; a0[3] = ae[3] + ao[3];

    // 1b. refill af with tile t+1's frags — full-tile latency window (WAR keeps
    // each load after its MFMA; drains at next tile's first MFMA via compiler vmcnt)
    {
      const int tn = (t < NT - 1) ? t + 1 : t;
      const char* gb = CH2c + (size_t)tn * 32768 + afo;
#pragma unroll
      for (int kc = 0; kc < 16; ++kc)
        af[kc] = *(const half8*)(gb + kc * 2048);
    }

    // 2. scores, top2, gumbel, z (lane: row rs*16+l15, codes cbase..+4)
    f32x4 zz; float mw = -3e38f;
    {
      const int cbase = t*32 + cs*16 + l4*4;
#pragma unroll
      for (int r = 0; r < 4; ++r) {
        float s = a0[r] - c2pre[r];                 // 2 x.c - |c|^2
        if (s > v1) { v2 = v1; i2 = i1; v1 = s; i1 = cbase + r; }
        else if (s > v2) { v2 = s; i2 = cbase + r; }
        float li = flog2(upre[r] + 1e-10f);
        float y  = fmaf(li, -LN2, 1e-10f);
        float g  = flog2(y) * (-LN2);
        float z  = (s + g) * c1;
        zz[r] = z;
        mw = fmaxf(mw, z);
      }
    }
    mw = fmaxf(mw, __shfl_xor(mw, 16, 64));
    mw = fmaxf(mw, __shfl_xor(mw, 32, 64));
    if (l < 16) mtab[w*16 + l] = mw;

    // B1: lgkm-only (mtab visible); all VMEM rides through
    asm volatile("s_waitcnt lgkmcnt(0)" ::: "memory");
    __builtin_amdgcn_s_barrier();
    __builtin_amdgcn_sched_barrier(0);

    // 3. per-row-half alphas, defer-max THR (T13); m_own == mO[rs]
    float alphaO[2];
#pragma unroll
    for (int rt = 0; rt < 2; ++rt) {
      float mt = fmaxf(mtab[(2*rt)*16 + l15], mtab[(2*rt + 1)*16 + l15]);
      float mo = mO[rt];
      float mn = (mt > mo + DEFER_THR) ? mt : mo;
      alphaO[rt] = fexp2(mo - mn);
      mO[rt] = mn;
    }
    const float m_own = rs ? mO[1] : mO[0];
    const float a_own = rs ? alphaO[1] : alphaO[0];

    // 3.5 prefetch U/c2 for t+1 (compiler-tracked drain at next scores)
    if (t < NT - 1) {
      upre  = ntload4(ub + (size_t)(t + 1) * 32);
      c2pre = *(const f32x4*)(c2p + (t + 1) * 32);
    }

    // 4. p = exp2(z - m_own) (bounded 2^THR), swizzled dbuf write
    {
      char* pcur = smem + ((t & 1) << 11);
      float p0 = fexp2(zz[0] - m_own);
      float p1 = fexp2(zz[1] - m_own);
      float p2 = fexp2(zz[2] - m_own);
      float p3 = fexp2(zz[3] - m_own);
      l_run = l_run * a_own + ((p0 + p1) + (p2 + p3));
      const int u = cs*2 + (l4 >> 1);
      union { _Float16 h[4]; uint2 q; } pk;
      pk.h[0] = (_Float16)p0; pk.h[1] = (_Float16)p1;
      pk.h[2] = (_Float16)p2; pk.h[3] = (_Float16)p3;
      *(uint2*)(pcur + prow*64 + ((u ^ sxp) << 4) + ((l4 & 1) << 3)) = pk.q;
    }

    // 5. PV(t-1): O += CT(t-1) x P^T(t-1)  (ctf in regs from last iter)
    if (t > 0) {
      const char* pprev = smem + (((t - 1) & 1) << 11);
      half8 pf0 = *(const half8*)(pprev + l15*64        + ((l4 ^ sxp) << 4));
      half8 pf1 = *(const half8*)(pprev + (16 + l15)*64 + ((l4 ^ sxp) << 4));
#pragma unroll
      for (int dt = 0; dt < 8; ++dt) {
        O[dt][0] = MFMA(ctf[dt], pf0, O[dt][0]);
        O[dt][1] = MFMA(ctf[dt], pf1, O[dt][1]);
      }
    }

    // 6. CT frags for PV(t) (L2-hot pre-tiled layout, global-direct)
#pragma unroll
    for (int dt = 0; dt < 8; ++dt)
      ctf[dt] = *(const half8*)(CTTc + (size_t)t * 32768
                                + (size_t)(w*128 + dt*16 + l15) * 64
                                + ((l4 ^ (l15 & 3)) << 4));

    // 7. O rescale (rare with defer-max; after PV(t-1))
#pragma unroll
    for (int rt = 0; rt < 2; ++rt) {
      if (__any(alphaO[rt] != 1.0f)) {
        const float a_ = alphaO[rt];
#pragma unroll
        for (int dt = 0; dt < 8; ++dt) {
          O[dt][rt][0] *= a_; O[dt][rt][1] *= a_;
          O[dt][rt][2] *= a_; O[dt][rt][3] *= a_;
        }
      }
    }

    // B2: lgkm-only (p(t) visible for PV at t+1)
    __builtin_amdgcn_sched_barrier(0);
    asm volatile("s_waitcnt lgkmcnt(0)" ::: "memory");
    __builtin_amdgcn_s_barrier();
    __builtin_amdgcn_sched_barrier(0);
  }

  // final PV(NT-1)
  {
    const char* pprev = smem + (((NT - 1) & 1) << 11);
    half8 pf0 = *(const half8*)(pprev + l15*64        + ((l4 ^ sxp) << 4));
    half8 pf1 = *(const half8*)(pprev + (16 + l15)*64 + ((l4 ^ sxp) << 4));
#pragma unroll
    for (int dt = 0; dt < 8; ++dt) {
      O[dt][0] = MFMA(ctf[dt], pf0, O[dt][0]);
      O[dt][1] = MFMA(ctf[dt], pf1, O[dt][1]);
    }
  }

  // ================= epilogue =================
  float lt2 = l_run;
  lt2 += __shfl_xor(lt2, 16, 64);
  lt2 += __shfl_xor(lt2, 32, 64);
  {
    float bv1 = __shfl_xor(v1, 16, 64); int bi1 = __shfl_xor(i1, 16, 64);
    float bv2 = __shfl_xor(v2, 16, 64); int bi2 = __shfl_xor(i2, 16, 64);
    top2_merge(v1, i1, v2, i2, bv1, bi1, bv2, bi2);
    bv1 = __shfl_xor(v1, 32, 64); bi1 = __shfl_xor(i1, 32, 64);
    bv2 = __shfl_xor(v2, 32, 64); bi2 = __shfl_xor(i2, 32, 64);
    top2_merge(v1, i1, v2, i2, bv1, bi1, bv2, bi2);
  }
  float* ltab = (float*)(smem + 38144);            // [4][16]
  f32x4* atab = (f32x4*)(smem + 38400);            // [4][16] (v1,i1,v2,i2)
  if (l < 16) {
    ltab[w*16 + l] = lt2;
    f32x4 pk;
    pk[0] = v1; pk[1] = __int_as_float(i1); pk[2] = v2; pk[3] = __int_as_float(i2);
    atab[w*16 + l] = pk;
  }
  __syncthreads();

  const float invr0 = 1.0f / (ltab[l15] + ltab[16 + l15]);
  const float invr1 = 1.0f / (ltab[32 + l15] + ltab[48 + l15]);

  if (w == 0 && l < 32) {   // final per-row argmax + near-tie flagging
    const int rt = l >> 4, r15 = l & 15;
    f32x4 A = atab[(2*rt)*16 + r15];
    f32x4 B = atab[(2*rt + 1)*16 + r15];
    float V1 = A[0], V2 = A[2];
    int I1 = __float_as_int(A[1]), I2 = __float_as_int(A[3]);
    top2_merge(V1, I1, V2, I2, B[0], __float_as_int(B[1]), B[2], __float_as_int(B[3]));
    ids[row0 + l] = (float)I1;
    if (V1 - V2 <= MARGIN) {
      int qi = atomicAdd(fixcnt, 1);
      if (qi < QCAP) { fixq[qi*3] = row0 + l; fixq[qi*3 + 1] = I1; fixq[qi*3 + 2] = I2; }
    }
  }

  // staged, coalesced, non-temporal emb store: two passes of 16 rows
  float* stagef = (float*)(smem + 4096);   // [16][520] f32
#pragma unroll
  for (int h = 0; h < 2; ++h) {
    __syncthreads();
    const float iv = h ? invr1 : invr0;
#pragma unroll
    for (int dt = 0; dt < 8; ++dt) {
      f32x4 v = O[dt][h];
      v[0] *= iv; v[1] *= iv; v[2] *= iv; v[3] *= iv;
      *(f32x4*)(stagef + l15*520 + w*128 + dt*16 + l4*4) = v;
    }
    __syncthreads();
#pragma unroll
    for (int q = 0; q < 8; ++q) {
      const int c = q*256 + tid;
      const int r_ = c >> 7, col = c & 127;
      f32x4 v = *(const f32x4*)(stagef + r_*520 + col*4);
      __builtin_nontemporal_store(v,
          (f32x4*)(emb + (size_t)(row0 + h*16 + r_)*DIM + col*4));
    }
  }
}

// exact rescoring of flagged near-ties (f64)
__global__ void vq_fixup(const float* __restrict__ X, const float* __restrict__ C,
                         const int* __restrict__ fixcnt, const int* __restrict__ fixq,
                         float* __restrict__ ids) {
  const int nw = (gridDim.x * blockDim.x) >> 6;
  const int gw = (blockIdx.x * blockDim.x + threadIdx.x) >> 6;
  const int l = threadIdx.x & 63;
  int cnt = *fixcnt; if (cnt > QCAP) cnt = QCAP;
  for (int q = gw; q < cnt; q += nw) {
    const int row = fixq[q*3], a = fixq[q*3 + 1], b = fixq[q*3 + 2];
    double da = 0, ca = 0, db = 0, cb = 0;
    for (int i = l; i < DIM; i += 64) {
      double xv = X[(size_t)row * DIM + i];
      double av = C[(size_t)a * DIM + i];
      double bv = C[(size_t)b * DIM + i];
      da += xv * av; ca += av * av;
      db += xv * bv; cb += bv * bv;
    }
#pragma unroll
    for (int o = 32; o; o >>= 1) {
      da += __shfl_down(da, o, 64); ca += __shfl_down(ca, o, 64);
      db += __shfl_down(db, o, 64); cb += __shfl_down(cb, o, 64);
    }
    if (l == 0) {
      double sa = 2.0 * da - ca, sb = 2.0 * db - cb;
      int win = (sb > sa || (sb == sa && b < a)) ? b : a;
      ids[row] = (float)win;
    }
  }
}

extern "C" void kernel_launch(void* const* d_in, const int* in_sizes, int n_in,
                              void* d_out, int out_size, void* d_ws, size_t ws_size,
                              hipStream_t stream) {
  (void)in_sizes; (void)n_in; (void)out_size; (void)ws_size;
  const float* x  = (const float*)d_in[0];
  const float* cb = (const float*)d_in[1];
  const float* u  = (const float*)d_in[2];
  const float* tp = (const float*)d_in[3];
  float* emb = (float*)d_out;
  float* ids = emb + (size_t)NROWS * DIM;

  char* ws = (char*)d_ws;
  int* fixcnt = (int*)ws;
  int* fixq = (int*)(ws + 256);
  size_t off = (256 + (size_t)QCAP * 12 + 511) & ~(size_t)511;
  _Float16* xh   = (_Float16*)(ws + off); off += (size_t)NROWS * DIM * 2;
  _Float16* cht2 = (_Float16*)(ws + off); off += (size_t)KC * DIM * 2;
  _Float16* ctt  = (_Float16*)(ws + off); off += (size_t)DIM * KC * 2;
  float* c2 = (float*)(ws + off);

  hipMemsetAsync(fixcnt, 0, 4, stream);
  prep_x   <<<(NROWS * DIM) / 1024, 256, 0, stream>>>(x, xh);
  prep_cht2<<<(KC * 64) / 256, 256, 0, stream>>>(cb, cht2);
  prep_ctt <<<(KC / 64) * (DIM / 64), 256, 0, stream>>>(cb, ctt);
  prep_c2  <<<KC / 4, 256, 0, stream>>>(cb, c2);
  vq_fused<<<NROWS / BM, 256, 0, stream>>>(u, xh, cht2, ctt, c2, tp, emb, ids, fixcnt, fixq);
  vq_fixup<<<32, 256, 0, stream>>>(x, cb, fixcnt, fixq, ids);
}

// Round 10
// 607.967 us; speedup vs baseline: 1.7401x; 1.7401x over previous
//
#include <hip/hip_runtime.h>

#define NROWS 16384
#define DIM   512
#define BM    32
#define NT    256            // KC / KTILE
#define KC    8192
#define QCAP  32768
#define MARGIN 0.05f
#define DEFER_THR 8.0f
#define LN2   0.69314718055994531f

typedef _Float16 half8  __attribute__((ext_vector_type(8)));
typedef float    f32x4  __attribute__((ext_vector_type(4)));
typedef unsigned int u32;

#define MFMA(a,b,c) __builtin_amdgcn_mfma_f32_16x16x32_f16(a,b,c,0,0,0)

__device__ __forceinline__ float flog2(float x){ return __builtin_amdgcn_logf(x); }
__device__ __forceinline__ float fexp2(float x){ return __builtin_amdgcn_exp2f(x); }
__device__ __forceinline__ f32x4 ntload4(const float* p){
  return __builtin_nontemporal_load((const f32x4*)p);
}
__device__ __forceinline__ void gload16(const void* g, void* l){
  __builtin_amdgcn_global_load_lds(
      (const __attribute__((address_space(1))) u32*)g,
      (__attribute__((address_space(3))) u32*)l, 16, 0, 0);
}

__device__ __forceinline__ void top2_merge(float& v1, int& i1, float& v2, int& i2,
                                           float bv1, int bi1, float bv2, int bi2) {
  bool takeB = (bv1 > v1) || (bv1 == v1 && bi1 < i1);
  float nv1 = takeB ? bv1 : v1; int ni1 = takeB ? bi1 : i1;
  float cv  = takeB ? v1  : bv1; int ci = takeB ? i1  : bi1;
  float ov2 = takeB ? bv2 : v2;  int oi = takeB ? bi2 : i2;
  bool cb = (cv > ov2) || (cv == ov2 && ci < oi);
  v2 = cb ? cv : ov2; i2 = cb ? ci : oi;
  v1 = nv1; i1 = ni1;
}

// ---------------- prep kernels ----------------
// x pre-scaled by 2*c1 (c1 = log2e/T): scores come out of MFMA already in z-units.
__global__ void prep_x(const float* __restrict__ x, const float* __restrict__ Tp,
                       _Float16* __restrict__ xh) {
  const float s2 = 2.0f * 1.4426950408889634f / Tp[0];
  size_t i = (size_t)(blockIdx.x * blockDim.x + threadIdx.x) * 4;
  f32x4 v = *(const f32x4*)(x + i);
  _Float16 h4[4];
  h4[0] = (_Float16)(s2 * v[0]); h4[1] = (_Float16)(s2 * v[1]);
  h4[2] = (_Float16)(s2 * v[2]); h4[3] = (_Float16)(s2 * v[3]);
  *(uint2*)(xh + i) = *(uint2*)h4;
}

// codebook, tiled [256 t][32 c][512 d] f16, 16B-unit swizzled: u -> u^(c&7)
__global__ void prep_cht(const float* __restrict__ c, _Float16* __restrict__ cht) {
  const int gid = blockIdx.x * 256 + threadIdx.x;
  const int code = gid >> 6, u = gid & 63;
  f32x4 v0 = *(const f32x4*)(c + (size_t)code * DIM + u * 8);
  f32x4 v1 = *(const f32x4*)(c + (size_t)code * DIM + u * 8 + 4);
  half8 h;
#pragma unroll
  for (int q = 0; q < 4; ++q) { h[q] = (_Float16)v0[q]; h[4+q] = (_Float16)v1[q]; }
  const int t = code >> 5, cc = code & 31;
  *(half8*)((char*)cht + (size_t)t * 32768 + cc * 1024 + ((u ^ (cc & 7)) << 4)) = h;
}

// codebook^T, tiled [256 t][512 d][32 k] f16, unit -> u^(d&3)
__global__ void prep_ctt(const float* __restrict__ c, _Float16* __restrict__ ctt) {
  __shared__ _Float16 lt[64][72];
  const int kb = (blockIdx.x >> 3) * 64;
  const int db = (blockIdx.x & 7) * 64;
  {
    const int r = threadIdx.x >> 2, c4 = threadIdx.x & 3;
#pragma unroll
    for (int j = 0; j < 4; ++j) {
      f32x4 v = *(const f32x4*)(c + (size_t)(kb + r) * DIM + db + c4 * 16 + j * 4);
#pragma unroll
      for (int q = 0; q < 4; ++q) lt[r][c4 * 16 + j * 4 + q] = (_Float16)v[q];
    }
  }
  __syncthreads();
  {
    const int d = threadIdx.x >> 2, ks = threadIdx.x & 3;
    half8 o0, o1;
#pragma unroll
    for (int j = 0; j < 8; ++j) { o0[j] = lt[ks*16 + j][d]; o1[j] = lt[ks*16 + 8 + j][d]; }
    const int dg = db + d;
    const int t = (kb >> 5) + (ks >> 1);
    const int u0 = (ks & 1) * 2;
    char* base = (char*)ctt + (size_t)t * 32768 + (size_t)dg * 64;
    *(half8*)(base + ((u0       ^ (dg & 3)) << 4)) = o0;
    *(half8*)(base + (((u0 + 1) ^ (dg & 3)) << 4)) = o1;
  }
}

// c2 pre-scaled by c1
__global__ void prep_c2(const float* __restrict__ c, const float* __restrict__ Tp,
                        float* __restrict__ c2) {
  const int w = threadIdx.x >> 6, l = threadIdx.x & 63;
  const int code = blockIdx.x * 4 + w;
  double s = 0.0;
  for (int i = l; i < DIM; i += 64) { double v = c[(size_t)code * DIM + i]; s += v * v; }
#pragma unroll
  for (int o = 32; o; o >>= 1) s += __shfl_down(s, o, 64);
  if (l == 0) c2[code] = (float)s * (1.4426950408889634f / Tp[0]);
}

// ---------------- main fused kernel ----------------
// R6 memory system + 2-deep softmax pipeline => ONE barrier per tile.
// Iter t: m-update(mtab(t-1)) | PV(t-2) | ctf(t-1) | rescale | QK(t) | scores z(t) |
//         mtab(t) write | p(t-1) write | stage(t+1) | U/c2(t+1) | barrier vmcnt(2).
// LDS 71680: [0,64K) stage dbuf | [64K,68K) p dbuf | mtab dbuf 69632 | ltab/atab 70144+.
__global__ __launch_bounds__(256, 2) void vq_fused(
    const float* __restrict__ U, const _Float16* __restrict__ Xh,
    const _Float16* __restrict__ CHT, const _Float16* __restrict__ CTT,
    const float* __restrict__ C2, const float* __restrict__ Tp,
    float* __restrict__ emb, float* __restrict__ ids,
    int* __restrict__ fixcnt, int* __restrict__ fixq) {
  __shared__ __align__(16) char smem[71680];
  const int tid = threadIdx.x;
  const int w = tid >> 6, l = tid & 63, l15 = l & 15, l4 = l >> 4;
  const int cs = w & 1, rs = w >> 1;
  const int row0 = blockIdx.x * BM;
  const float c1 = 1.4426950408889634f / Tp[0];
  const float tinv = 1.0f / Tp[0];
  const char* CHTc = (const char*)CHT;
  const char* CTTc = (const char*)CTT;

  // x rows resident in registers: row rs*16+l15, all 512 d (pre-scaled by 2*c1)
  half8 xr[16];
  {
    const _Float16* xb = Xh + (size_t)(row0 + rs*16 + l15) * DIM + l4 * 8;
#pragma unroll
    for (int kc = 0; kc < 16; ++kc) xr[kc] = *(const half8*)(xb + kc * 32);
  }

  const int sxq = l15 & 7;                     // chA row-xor (64 units/row)
  const int sxp = (l15 ^ (l15 >> 2)) & 3;      // p/CTT row-xor (4 units/row)
  const int qkb = (cs*16 + l15) * 1024;        // QK A-row base
  const int prow = rs*16 + l15;                // p row this lane writes

  const float* ub  = U  + (size_t)(row0 + prow) * KC + cs*16 + l4*4;
  const float* c2p = C2 + cs*16 + l4*4;

  f32x4 upre  = ntload4(ub);
  f32x4 c2pre = *(const f32x4*)(c2p);

  // stage tile 0
  {
    const char* g = CHTc + (size_t)(w*64 + l) * 16;
    char* lb = smem + w * 1024;
#pragma unroll
    for (int r = 0; r < 8; ++r) gload16(g + r * 4096, lb + r * 4096);
  }

  f32x4 O[8][2];   // [dt: d=w*128+dt*16][rt: row half]
#pragma unroll
  for (int a = 0; a < 8; ++a)
#pragma unroll
    for (int b = 0; b < 2; ++b) { O[a][b][0]=0.f; O[a][b][1]=0.f; O[a][b][2]=0.f; O[a][b][3]=0.f; }
  half8 ctf[8];
  f32x4 z_prev;
  float mO[2] = {-3e38f, -3e38f};
  float l_run = 0.f;
  float v1 = -3e38f, v2 = -3e38f; int i1 = 0, i2 = 0;

  __syncthreads();   // tile 0 staged (full drain, once)

#pragma unroll 1
  for (int t = 0; t < NT; ++t) {
    // ---- 1. m-update from mtab(t-1) (written pre-barrier(t-1)) ----
    float alphaO[2] = {1.0f, 1.0f};
    if (t > 0) {
      const float* mt_ = (const float*)(smem + 69632 + (((t - 1) & 1) << 8));
#pragma unroll
      for (int rt = 0; rt < 2; ++rt) {
        float m2 = fmaxf(mt_[(2*rt)*16 + l15], mt_[(2*rt + 1)*16 + l15]);
        float mo = mO[rt];
        float mn = (m2 > mo + DEFER_THR) ? m2 : mo;
        alphaO[rt] = fexp2(mo - mn);
        mO[rt] = mn;
      }
      l_run *= (rs ? alphaO[1] : alphaO[0]);
    }
    const float m_own = rs ? mO[1] : mO[0];

    // ---- 2. PV(t-2): p slot (t&1), ctf = tile (t-2) frags loaded last iter ----
    if (t >= 2) {
      const char* pprev = smem + 65536 + ((t & 1) << 11);
      half8 pf0 = *(const half8*)(pprev + l15*64        + ((l4 ^ sxp) << 4));
      half8 pf1 = *(const half8*)(pprev + (16 + l15)*64 + ((l4 ^ sxp) << 4));
#pragma unroll
      for (int dt = 0; dt < 8; ++dt) {
        O[dt][0] = MFMA(ctf[dt], pf0, O[dt][0]);
        O[dt][1] = MFMA(ctf[dt], pf1, O[dt][1]);
      }
    }

    // ---- 2.5 ctf for tile (t-1) (used by PV(t-1) at iter t+1); issued FIRST
    //      among this iter's VMEM so the barrier's vmcnt retires it with stage ----
    {
      const int tc = (t > 0) ? t - 1 : 0;
#pragma unroll
      for (int dt = 0; dt < 8; ++dt)
        ctf[dt] = *(const half8*)(CTTc + (size_t)tc * 32768
                                  + (size_t)(w*128 + dt*16 + l15) * 64
                                  + ((l4 ^ (l15 & 3)) << 4));
    }

    // ---- 3. O rescale to m(t-1) (after PV(t-2) at old scale) ----
#pragma unroll
    for (int rt = 0; rt < 2; ++rt) {
      if (__any(alphaO[rt] != 1.0f)) {
        const float a_ = alphaO[rt];
#pragma unroll
        for (int dt = 0; dt < 8; ++dt) {
          O[dt][rt][0] *= a_; O[dt][rt][1] *= a_;
          O[dt][rt][2] *= a_; O[dt][rt][3] *= a_;
        }
      }
    }

    // ---- 4. QK(t): A from LDS stage slot (t&1), B from regs ----
    const char* chc = smem + ((t & 1) << 15);
    f32x4 a0 = {0.f, 0.f, 0.f, 0.f};
#pragma unroll
    for (int kc = 0; kc < 16; ++kc) {
      half8 A0 = *(const half8*)(chc + qkb + (((kc*4 + l4) ^ sxq) << 4));
      a0 = MFMA(A0, xr[kc], a0);
    }

    // ---- 5. scores (already z-scaled), top2, gumbel, z(t) ----
    f32x4 zz; float mw = -3e38f;
    {
      const int cbase = t*32 + cs*16 + l4*4;
#pragma unroll
      for (int r = 0; r < 4; ++r) {
        float s = a0[r] - c2pre[r];                 // c1*(2 x.c - |c|^2)
        if (s > v1) { v2 = v1; i2 = i1; v1 = s; i1 = cbase + r; }
        else if (s > v2) { v2 = s; i2 = cbase + r; }
        float li = flog2(upre[r] + 1e-10f);
        float y  = fmaf(li, -LN2, 1e-10f);
        float z  = fmaf(flog2(y), -tinv, s);        // s*c1 + g*c1 folded
        zz[r] = z;
        mw = fmaxf(mw, z);
      }
    }
    mw = fmaxf(mw, __shfl_xor(mw, 16, 64));
    mw = fmaxf(mw, __shfl_xor(mw, 32, 64));

    // ---- 6. mtab(t) write (slot t&1) ----
    if (l < 16) ((float*)(smem + 69632 + ((t & 1) << 8)))[w*16 + l] = mw;

    // ---- 7. p(t-1) = exp2(z_prev - m(t-1)) -> slot ((t-1)&1) ----
    if (t > 0) {
      char* pcur = smem + 65536 + (((t - 1) & 1) << 11);
      float p0 = fexp2(z_prev[0] - m_own);
      float p1 = fexp2(z_prev[1] - m_own);
      float p2 = fexp2(z_prev[2] - m_own);
      float p3 = fexp2(z_prev[3] - m_own);
      l_run += (p0 + p1) + (p2 + p3);
      const int u = cs*2 + (l4 >> 1);
      union { _Float16 h[4]; uint2 q; } pk;
      pk.h[0] = (_Float16)p0; pk.h[1] = (_Float16)p1;
      pk.h[2] = (_Float16)p2; pk.h[3] = (_Float16)p3;
      *(uint2*)(pcur + prow*64 + ((u ^ sxp) << 4) + ((l4 & 1) << 3)) = pk.q;
    }
    z_prev = zz;

    // ---- 8. stage(t+1) (consumed right after barrier(t)) ----
    if (t < NT - 1) {
      const char* g = CHTc + ((size_t)(t + 1)) * 32768 + (size_t)(w*64 + l) * 16;
      char* lb = smem + (((t + 1) & 1) << 15) + w * 1024;
#pragma unroll
      for (int r = 0; r < 8; ++r) gload16(g + r * 4096, lb + r * 4096);
    }

    // ---- 9. U/c2 prefetch (t+1) — youngest, rides through the barrier ----
    if (t < NT - 1) {
      upre  = ntload4(ub + (size_t)(t + 1) * 32);
      c2pre = *(const f32x4*)(c2p + (t + 1) * 32);
    }

    // ---- 10. THE barrier: retire ctf+stage (16 oldest), let U/c2 ride ----
    __builtin_amdgcn_sched_barrier(0);
    asm volatile("s_waitcnt vmcnt(2) lgkmcnt(0)" ::: "memory");
    __builtin_amdgcn_s_barrier();
    __builtin_amdgcn_sched_barrier(0);
  }

  // ---- epilogue A: finish pipeline (iter NT without QK/scores/stage) ----
  {
    float alphaO[2];
    const float* mt_ = (const float*)(smem + 69632 + (((NT - 1) & 1) << 8));
#pragma unroll
    for (int rt = 0; rt < 2; ++rt) {
      float m2 = fmaxf(mt_[(2*rt)*16 + l15], mt_[(2*rt + 1)*16 + l15]);
      float mo = mO[rt];
      float mn = (m2 > mo + DEFER_THR) ? m2 : mo;
      alphaO[rt] = fexp2(mo - mn);
      mO[rt] = mn;
    }
    l_run *= (rs ? alphaO[1] : alphaO[0]);
    const float m_own = rs ? mO[1] : mO[0];

    // PV(NT-2): slot (NT&1)
    {
      const char* pprev = smem + 65536 + ((NT & 1) << 11);
      half8 pf0 = *(const half8*)(pprev + l15*64        + ((l4 ^ sxp) << 4));
      half8 pf1 = *(const half8*)(pprev + (16 + l15)*64 + ((l4 ^ sxp) << 4));
#pragma unroll
      for (int dt = 0; dt < 8; ++dt) {
        O[dt][0] = MFMA(ctf[dt], pf0, O[dt][0]);
        O[dt][1] = MFMA(ctf[dt], pf1, O[dt][1]);
      }
    }
    // ctf for tile NT-1
#pragma unroll
    for (int dt = 0; dt < 8; ++dt)
      ctf[dt] = *(const half8*)(CTTc + (size_t)(NT - 1) * 32768
                                + (size_t)(w*128 + dt*16 + l15) * 64
                                + ((l4 ^ (l15 & 3)) << 4));
    // rescale to m(NT-1)
#pragma unroll
    for (int rt = 0; rt < 2; ++rt) {
      if (__any(alphaO[rt] != 1.0f)) {
        const float a_ = alphaO[rt];
#pragma unroll
        for (int dt = 0; dt < 8; ++dt) {
          O[dt][rt][0] *= a_; O[dt][rt][1] *= a_;
          O[dt][rt][2] *= a_; O[dt][rt][3] *= a_;
        }
      }
    }
    // p(NT-1) write: slot ((NT-1)&1)
    {
      char* pcur = smem + 65536 + (((NT - 1) & 1) << 11);
      float p0 = fexp2(z_prev[0] - m_own);
      float p1 = fexp2(z_prev[1] - m_own);
      float p2 = fexp2(z_prev[2] - m_own);
      float p3 = fexp2(z_prev[3] - m_own);
      l_run += (p0 + p1) + (p2 + p3);
      const int u = cs*2 + (l4 >> 1);
      union { _Float16 h[4]; uint2 q; } pk;
      pk.h[0] = (_Float16)p0; pk.h[1] = (_Float16)p1;
      pk.h[2] = (_Float16)p2; pk.h[3] = (_Float16)p3;
      *(uint2*)(pcur + prow*64 + ((u ^ sxp) << 4) + ((l4 & 1) << 3)) = pk.q;
    }
    asm volatile("s_waitcnt lgkmcnt(0)" ::: "memory");
    __builtin_amdgcn_s_barrier();
    // PV(NT-1)
    {
      const char* pprev = smem + 65536 + (((NT - 1) & 1) << 11);
      half8 pf0 = *(const half8*)(pprev + l15*64        + ((l4 ^ sxp) << 4));
      half8 pf1 = *(const half8*)(pprev + (16 + l15)*64 + ((l4 ^ sxp) << 4));
#pragma unroll
      for (int dt = 0; dt < 8; ++dt) {
        O[dt][0] = MFMA(ctf[dt], pf0, O[dt][0]);
        O[dt][1] = MFMA(ctf[dt], pf1, O[dt][1]);
      }
    }
  }

  // ================= epilogue =================
  float lt2 = l_run;
  lt2 += __shfl_xor(lt2, 16, 64);
  lt2 += __shfl_xor(lt2, 32, 64);
  {
    float bv1 = __shfl_xor(v1, 16, 64); int bi1 = __shfl_xor(i1, 16, 64);
    float bv2 = __shfl_xor(v2, 16, 64); int bi2 = __shfl_xor(i2, 16, 64);
    top2_merge(v1, i1, v2, i2, bv1, bi1, bv2, bi2);
    bv1 = __shfl_xor(v1, 32, 64); bi1 = __shfl_xor(i1, 32, 64);
    bv2 = __shfl_xor(v2, 32, 64); bi2 = __shfl_xor(i2, 32, 64);
    top2_merge(v1, i1, v2, i2, bv1, bi1, bv2, bi2);
  }
  float* ltab = (float*)(smem + 70144);            // [4][16]
  f32x4* atab = (f32x4*)(smem + 70400);            // [4][16]
  __syncthreads();
  if (l < 16) {
    ltab[w*16 + l] = lt2;
    f32x4 pk;
    pk[0] = v1; pk[1] = __int_as_float(i1); pk[2] = v2; pk[3] = __int_as_float(i2);
    atab[w*16 + l] = pk;
  }
  __syncthreads();

  const float invr0 = 1.0f / (ltab[l15] + ltab[16 + l15]);
  const float invr1 = 1.0f / (ltab[32 + l15] + ltab[48 + l15]);

  if (w == 0 && l < 32) {   // final per-row argmax + near-tie flagging
    const int rt = l >> 4, r15 = l & 15;
    f32x4 A = atab[(2*rt)*16 + r15];
    f32x4 B = atab[(2*rt + 1)*16 + r15];
    float V1 = A[0], V2 = A[2];
    int I1 = __float_as_int(A[1]), I2 = __float_as_int(A[3]);
    top2_merge(V1, I1, V2, I2, B[0], __float_as_int(B[1]), B[2], __float_as_int(B[3]));
    ids[row0 + l] = (float)I1;
    if (V1 - V2 <= MARGIN * c1) {   // scores are c1-scaled
      int qi = atomicAdd(fixcnt, 1);
      if (qi < QCAP) { fixq[qi*3] = row0 + l; fixq[qi*3 + 1] = I1; fixq[qi*3 + 2] = I2; }
    }
  }

  // staged, coalesced, non-temporal emb store: two passes of 16 rows
  float* stagef = (float*)smem;   // [16][520] f32 (stage region reuse)
#pragma unroll
  for (int h = 0; h < 2; ++h) {
    __syncthreads();
    const float iv = h ? invr1 : invr0;
#pragma unroll
    for (int dt = 0; dt < 8; ++dt) {
      f32x4 v = O[dt][h];
      v[0] *= iv; v[1] *= iv; v[2] *= iv; v[3] *= iv;
      *(f32x4*)(stagef + l15*520 + w*128 + dt*16 + l4*4) = v;
    }
    __syncthreads();
#pragma unroll
    for (int q = 0; q < 8; ++q) {
      const int c = q*256 + tid;
      const int r_ = c >> 7, col = c & 127;
      f32x4 v = *(const f32x4*)(stagef + r_*520 + col*4);
      __builtin_nontemporal_store(v,
          (f32x4*)(emb + (size_t)(row0 + h*16 + r_)*DIM + col*4));
    }
  }
}

// exact rescoring of flagged near-ties (f64)
__global__ void vq_fixup(const float* __restrict__ X, const float* __restrict__ C,
                         const int* __restrict__ fixcnt, const int* __restrict__ fixq,
                         float* __restrict__ ids) {
  const int nw = (gridDim.x * blockDim.x) >> 6;
  const int gw = (blockIdx.x * blockDim.x + threadIdx.x) >> 6;
  const int l = threadIdx.x & 63;
  int cnt = *fixcnt; if (cnt > QCAP) cnt = QCAP;
  for (int q = gw; q < cnt; q += nw) {
    const int row = fixq[q*3], a = fixq[q*3 + 1], b = fixq[q*3 + 2];
    double da = 0, ca = 0, db = 0, cb = 0;
    for (int i = l; i < DIM; i += 64) {
      double xv = X[(size_t)row * DIM + i];
      double av = C[(size_t)a * DIM + i];
      double bv = C[(size_t)b * DIM + i];
      da += xv * av; ca += av * av;
      db += xv * bv; cb += bv * bv;
    }
#pragma unroll
    for (int o = 32; o; o >>= 1) {
      da += __shfl_down(da, o, 64); ca += __shfl_down(ca, o, 64);
      db += __shfl_down(db, o, 64); cb += __shfl_down(cb, o, 64);
    }
    if (l == 0) {
      double sa = 2.0 * da - ca, sb = 2.0 * db - cb;
      int win = (sb > sa || (sb == sa && b < a)) ? b : a;
      ids[row] = (float)win;
    }
  }
}

extern "C" void kernel_launch(void* const* d_in, const int* in_sizes, int n_in,
                              void* d_out, int out_size, void* d_ws, size_t ws_size,
                              hipStream_t stream) {
  (void)in_sizes; (void)n_in; (void)out_size; (void)ws_size;
  const float* x  = (const float*)d_in[0];
  const float* cb = (const float*)d_in[1];
  const float* u  = (const float*)d_in[2];
  const float* tp = (const float*)d_in[3];
  float* emb = (float*)d_out;
  float* ids = emb + (size_t)NROWS * DIM;

  char* ws = (char*)d_ws;
  int* fixcnt = (int*)ws;
  int* fixq = (int*)(ws + 256);
  size_t off = (256 + (size_t)QCAP * 12 + 511) & ~(size_t)511;
  _Float16* xh  = (_Float16*)(ws + off); off += (size_t)NROWS * DIM * 2;
  _Float16* cht = (_Float16*)(ws + off); off += (size_t)KC * DIM * 2;
  _Float16* ctt = (_Float16*)(ws + off); off += (size_t)DIM * KC * 2;
  float* c2 = (float*)(ws + off);

  hipMemsetAsync(fixcnt, 0, 4, stream);
  prep_x  <<<(NROWS * DIM) / 1024, 256, 0, stream>>>(x, tp, xh);
  prep_cht<<<(KC * 64) / 256, 256, 0, stream>>>(cb, cht);
  prep_ctt<<<(KC / 64) * (DIM / 64), 256, 0, stream>>>(cb, ctt);
  prep_c2 <<<KC / 4, 256, 0, stream>>>(cb, tp, c2);
  vq_fused<<<NROWS / BM, 256, 0, stream>>>(u, xh, cht, ctt, c2, tp, emb, ids, fixcnt, fixq);
  vq_fixup<<<32, 256, 0, stream>>>(x, cb, fixcnt, fixq, ids);
}